// Round 5
// baseline (928.253 us; speedup 1.0000x reference)
//
#include <hip/hip_runtime.h>
#include <hip/hip_bf16.h>

// ---------------------------------------------------------------------------
// GCN 3-layer, N=50000, E=800000, D=64, fp32 in/out.
// R18: persistent mega-kernel with SOFTWARE grid barrier. R17's cooperative
// launch produced all-zero output (absmax 1.75 == max|ref|): the launch
// itself never executed (error swallowed; graph-capture or validation
// rejection). Phase/queue logic re-audited clean, so keep the structure and
// replace cg::grid.sync() with a monotonic spin barrier: host memset zeroes
// a control block (bar + queues); barrier = atomicAdd arrive + spin until
// count >= nblocks*phase, bracketed by __threadfence() (agent-scope
// release/acquire handles cross-XCD L2 non-coherence; atomics are
// device-coherent). Co-residency by construction: grid=1024 = 256CU x
// 4 blocks/CU at launch_bounds(256,4) (<=128 VGPR, 12.4KB LDS -> 49.6KB/CU).
// s_sleep(8) polling keeps one-address atomic contention harmless.
// Phases: P1 fill (per-XCD-class queues) -> P2 gemm1 -> P3 aggemm(W2)
// -> P4 aggemm(W3) -> P5 final agg. Bodies bit-identical R15: 8-lane/node
// uint4 gather with index prefetch, agg+gemm fusion through LDS A-frags,
// bucket adjacency CAP=64, bf16 g-table, MFMA 16x16x32.
// ---------------------------------------------------------------------------

#define CAP 64
#define EDGE_CHUNK 1024
#define NBLK 1024

typedef __attribute__((ext_vector_type(8))) short bf16x8;
typedef __attribute__((ext_vector_type(4))) float f32x4;

// --- pack two fp32 -> bf16x2 (RNE) ----------------------------------------
__device__ inline unsigned pack_bf16(float a, float b) {
    union { float f; unsigned i; } ua, ub;
    ua.f = a; ub.f = b;
    unsigned x = (ua.i + 0x7fffu + ((ua.i >> 16) & 1u)) >> 16;
    unsigned y = (ub.i + 0x7fffu + ((ub.i >> 16) & 1u)) >> 16;
    return x | (y << 16);
}
__device__ inline unsigned short to_bf16(float a) {
    union { float f; unsigned i; } u; u.f = a;
    return (unsigned short)((u.i + 0x7fffu + ((u.i >> 16) & 1u)) >> 16);
}
// --- accumulate bf16x2 (packed uint) into two floats ----------------------
__device__ inline void acc_bf16x2(unsigned u, float& a, float& b) {
    union { unsigned i; float f; } lo, hi;
    lo.i = u << 16;
    hi.i = u & 0xffff0000u;
    a += lo.f; b += hi.f;
}

// --- monotonic grid barrier (ctl[0] zeroed by host memset each launch) ----
__device__ inline void grid_barrier(int* __restrict__ bar, int phase) {
    __syncthreads();
    if (threadIdx.x == 0) {
        __threadfence();                       // release (agent scope)
        atomicAdd(bar, 1);
        const int target = NBLK * phase;
        while (atomicAdd(bar, 0) < target)
            __builtin_amdgcn_s_sleep(8);
        __threadfence();                       // acquire (agent scope)
    }
    __syncthreads();
}

// --- 8-lane/node uint4 row gather with index prefetch (R15 form) ----------
__device__ inline void gather_rows(const unsigned short* __restrict__ g,
                                   const int* __restrict__ lst, int deg, int c8,
                                   float& a0, float& a1, float& a2, float& a3,
                                   float& a4, float& a5, float& a6, float& a7) {
    int nfull = deg >> 3;              // full 8-batches
    int4 ja, jb;
    if (nfull > 0) { ja = *(const int4*)&lst[0]; jb = *(const int4*)&lst[4]; }
    for (int b = 0; b < nfull; b++) {
        int4 na = ja, nb = jb;         // prefetch next batch's indices
        if (b + 1 < nfull) {
            na = *(const int4*)&lst[(b + 1) * 8];
            nb = *(const int4*)&lst[(b + 1) * 8 + 4];
        }
        uint4 w0 = *(const uint4*)&g[(size_t)ja.x * 64 + c8];
        uint4 w1 = *(const uint4*)&g[(size_t)ja.y * 64 + c8];
        uint4 w2 = *(const uint4*)&g[(size_t)ja.z * 64 + c8];
        uint4 w3 = *(const uint4*)&g[(size_t)ja.w * 64 + c8];
        uint4 w4 = *(const uint4*)&g[(size_t)jb.x * 64 + c8];
        uint4 w5 = *(const uint4*)&g[(size_t)jb.y * 64 + c8];
        uint4 w6 = *(const uint4*)&g[(size_t)jb.z * 64 + c8];
        uint4 w7 = *(const uint4*)&g[(size_t)jb.w * 64 + c8];
        acc_bf16x2(w0.x, a0, a1); acc_bf16x2(w0.y, a2, a3);
        acc_bf16x2(w0.z, a4, a5); acc_bf16x2(w0.w, a6, a7);
        acc_bf16x2(w1.x, a0, a1); acc_bf16x2(w1.y, a2, a3);
        acc_bf16x2(w1.z, a4, a5); acc_bf16x2(w1.w, a6, a7);
        acc_bf16x2(w2.x, a0, a1); acc_bf16x2(w2.y, a2, a3);
        acc_bf16x2(w2.z, a4, a5); acc_bf16x2(w2.w, a6, a7);
        acc_bf16x2(w3.x, a0, a1); acc_bf16x2(w3.y, a2, a3);
        acc_bf16x2(w3.z, a4, a5); acc_bf16x2(w3.w, a6, a7);
        acc_bf16x2(w4.x, a0, a1); acc_bf16x2(w4.y, a2, a3);
        acc_bf16x2(w4.z, a4, a5); acc_bf16x2(w4.w, a6, a7);
        acc_bf16x2(w5.x, a0, a1); acc_bf16x2(w5.y, a2, a3);
        acc_bf16x2(w5.z, a4, a5); acc_bf16x2(w5.w, a6, a7);
        acc_bf16x2(w6.x, a0, a1); acc_bf16x2(w6.y, a2, a3);
        acc_bf16x2(w6.z, a4, a5); acc_bf16x2(w6.w, a6, a7);
        acc_bf16x2(w7.x, a0, a1); acc_bf16x2(w7.y, a2, a3);
        acc_bf16x2(w7.z, a4, a5); acc_bf16x2(w7.w, a6, a7);
        ja = na; jb = nb;
    }
    int k = nfull * 8;
    if (k + 4 <= deg) {
        int4 j4 = *(const int4*)&lst[k];
        uint4 w0 = *(const uint4*)&g[(size_t)j4.x * 64 + c8];
        uint4 w1 = *(const uint4*)&g[(size_t)j4.y * 64 + c8];
        uint4 w2 = *(const uint4*)&g[(size_t)j4.z * 64 + c8];
        uint4 w3 = *(const uint4*)&g[(size_t)j4.w * 64 + c8];
        acc_bf16x2(w0.x, a0, a1); acc_bf16x2(w0.y, a2, a3);
        acc_bf16x2(w0.z, a4, a5); acc_bf16x2(w0.w, a6, a7);
        acc_bf16x2(w1.x, a0, a1); acc_bf16x2(w1.y, a2, a3);
        acc_bf16x2(w1.z, a4, a5); acc_bf16x2(w1.w, a6, a7);
        acc_bf16x2(w2.x, a0, a1); acc_bf16x2(w2.y, a2, a3);
        acc_bf16x2(w2.z, a4, a5); acc_bf16x2(w2.w, a6, a7);
        acc_bf16x2(w3.x, a0, a1); acc_bf16x2(w3.y, a2, a3);
        acc_bf16x2(w3.z, a4, a5); acc_bf16x2(w3.w, a6, a7);
        k += 4;
    }
    for (; k < deg; k++) {
        uint4 v = *(const uint4*)&g[(size_t)lst[k] * 64 + c8];
        acc_bf16x2(v.x, a0, a1); acc_bf16x2(v.y, a2, a3);
        acc_bf16x2(v.z, a4, a5); acc_bf16x2(v.w, a6, a7);
    }
}

// --- stage W (fp32 64x64) into B-fragment order (bf16) in LDS -------------
__device__ inline void stage_W(const float* __restrict__ W, unsigned short* Wb, int t) {
#pragma unroll
    for (int e0 = 0; e0 < 2; e0++) {
        int e = t + e0 * 256;          // frag index 0..511
        int sc = e >> 6;               // s*4 + c
        int l  = e & 63;               // target lane
        int s = sc >> 2, c = sc & 3;
        int nn = c * 16 + (l & 15);
        int kb = s * 32 + (l >> 4) * 8;
        const float* wp = &W[(size_t)kb * 64 + nn];
        unsigned q0 = pack_bf16(wp[0 * 64], wp[1 * 64]);
        unsigned q1 = pack_bf16(wp[2 * 64], wp[3 * 64]);
        unsigned q2 = pack_bf16(wp[4 * 64], wp[5 * 64]);
        unsigned q3 = pack_bf16(wp[6 * 64], wp[7 * 64]);
        *(uint4*)&Wb[e * 8] = make_uint4(q0, q1, q2, q3);
    }
}

// --- fused agg + gemm phase body (R15 aggemm, queue-driven) ---------------
__device__ inline void aggemm_phase(
        const unsigned short* __restrict__ g_in,
        const int* __restrict__ cnt,
        const int* __restrict__ adj,
        const float* __restrict__ bias,
        const float* __restrict__ res,
        float* __restrict__ h_out,          // nullptr => don't write h
        unsigned short* __restrict__ g_out,
        int n, int* __restrict__ myq,
        unsigned short* Wb, unsigned short* Afrag, float* dsh, int* qsp,
        int t) {
    const int r  = t >> 3;             // node-in-block 0..31
    const int lg = t & 7;
    const int c8 = lg * 8;
    const int wv = t >> 6, lane = t & 63, quad = lane >> 4, m16 = lane & 15;
    const int sB = wv & 1, ch = wv >> 1;
    const int groups = (n + 31) / 32;
    for (;;) {
        __syncthreads();               // protect qs/Afrag/dsh from prev iter
        if (t == 0) *qsp = atomicAdd(myq, 1);
        __syncthreads();
        int u = *qsp;
        if (u >= groups) break;

        // ---- Phase A: aggregate 32 nodes, 8 lanes/node, uint4 ----
        int i = u * 32 + r;
        float v0 = 0.f, v1 = 0.f, v2 = 0.f, v3 = 0.f;
        float v4 = 0.f, v5 = 0.f, v6 = 0.f, v7 = 0.f;
        float dvv = 0.f;
        if (i < n) {
            int deg = cnt[i];
            const int* lst = adj + (size_t)i * CAP;
            float4 rr0 = *(const float4*)&res[(size_t)i * 64 + c8];
            float4 rr1 = *(const float4*)&res[(size_t)i * 64 + c8 + 4];
            float a0 = 0.f, a1 = 0.f, a2 = 0.f, a3 = 0.f;
            float a4 = 0.f, a5 = 0.f, a6 = 0.f, a7 = 0.f;
            {   // self loop
                uint4 v = *(const uint4*)&g_in[(size_t)i * 64 + c8];
                acc_bf16x2(v.x, a0, a1); acc_bf16x2(v.y, a2, a3);
                acc_bf16x2(v.z, a4, a5); acc_bf16x2(v.w, a6, a7);
            }
            gather_rows(g_in, lst, deg, c8, a0, a1, a2, a3, a4, a5, a6, a7);
            dvv = rsqrtf((float)(deg + 1));
            float4 b0 = *(const float4*)&bias[c8];
            float4 b1 = *(const float4*)&bias[c8 + 4];
            v0 = fmaxf(dvv * a0 + b0.x, 0.f) + rr0.x;
            v1 = fmaxf(dvv * a1 + b0.y, 0.f) + rr0.y;
            v2 = fmaxf(dvv * a2 + b0.z, 0.f) + rr0.z;
            v3 = fmaxf(dvv * a3 + b0.w, 0.f) + rr0.w;
            v4 = fmaxf(dvv * a4 + b1.x, 0.f) + rr1.x;
            v5 = fmaxf(dvv * a5 + b1.y, 0.f) + rr1.y;
            v6 = fmaxf(dvv * a6 + b1.z, 0.f) + rr1.z;
            v7 = fmaxf(dvv * a7 + b1.w, 0.f) + rr1.w;
            if (h_out) {
                *(float4*)&h_out[(size_t)i * 64 + c8]     = make_float4(v0, v1, v2, v3);
                *(float4*)&h_out[(size_t)i * 64 + c8 + 4] = make_float4(v4, v5, v6, v7);
            }
        }
        // deposit into A-frag LDS (zeros for i>=n)
        {
            uint4 pk;
            pk.x = pack_bf16(v0, v1);
            pk.y = pack_bf16(v2, v3);
            pk.z = pack_bf16(v4, v5);
            pk.w = pack_bf16(v6, v7);
            int sA = r >> 4, mA = r & 15;
            *(uint4*)&Afrag[((size_t)(sA * 8 + lg) * 16 + mA) * 8] = pk;
            if (lg == 0) dsh[r] = dvv;
        }
        __syncthreads();

        // ---- Phase B: MFMA gemm on the 32-row tile ----
        bf16x8 af0 = *(const bf16x8*)&Afrag[((size_t)(sB * 8 + quad) * 16 + m16) * 8];
        bf16x8 af1 = *(const bf16x8*)&Afrag[((size_t)(sB * 8 + 4 + quad) * 16 + m16) * 8];
        f32x4 acc[2];
#pragma unroll
        for (int c2 = 0; c2 < 2; c2++) {
            int c = ch * 2 + c2;
            bf16x8 b0 = *(const bf16x8*)&Wb[((size_t)(0 * 4 + c) * 64 + lane) * 8];
            bf16x8 b1 = *(const bf16x8*)&Wb[((size_t)(1 * 4 + c) * 64 + lane) * 8];
            f32x4 z = {0.f, 0.f, 0.f, 0.f};
            z = __builtin_amdgcn_mfma_f32_16x16x32_bf16(af0, b0, z, 0, 0, 0);
            z = __builtin_amdgcn_mfma_f32_16x16x32_bf16(af1, b1, z, 0, 0, 0);
            acc[c2] = z;
        }
        int lrow = sB * 16 + quad * 4;
        int rowbase = u * 32 + lrow;
        float dv2[4];
#pragma unroll
        for (int rr = 0; rr < 4; rr++)
            dv2[rr] = dsh[lrow + rr];
#pragma unroll
        for (int c2 = 0; c2 < 2; c2++) {
            int c = ch * 2 + c2;
#pragma unroll
            for (int rr = 0; rr < 4; rr++) {
                int row = rowbase + rr;
                if (row < n)
                    g_out[(size_t)row * 64 + c * 16 + m16] = to_bf16(acc[c2][rr] * dv2[rr]);
            }
        }
    }
}

// --- the whole pipeline as one persistent kernel (software barrier) -------
__global__ __launch_bounds__(256, 4) void gcn_mega(
        const float* __restrict__ x,
        const int* __restrict__ src, const int* __restrict__ dstp,
        const float* __restrict__ W1, const float* __restrict__ b1,
        const float* __restrict__ W2, const float* __restrict__ b2,
        const float* __restrict__ W3, const float* __restrict__ b3,
        float* __restrict__ out,
        int* __restrict__ ctl,   // [0]=bar, [8..23]=queues (host-zeroed)
        int* __restrict__ cnt, int* __restrict__ adj,
        unsigned short* __restrict__ ga, unsigned short* __restrict__ gb,
        float* __restrict__ h1,
        int n, int E, int npc) {
    __shared__ unsigned short Wb[512 * 8];     // 8 KB B-frags
    __shared__ unsigned short Afrag[256 * 8];  // 4 KB A-frags
    __shared__ float dsh[32];
    __shared__ int qs;
    const int t = threadIdx.x;
    int* bar = ctl;

    // ---- P1: bucket adjacency fill (per-class queue -> XCD locality) ----
    {
        int cls = blockIdx.x & 7;      // blockIdx round-robin -> XCD
        int lo = cls * npc, hi = lo + npc;
        int nChunks = (E + EDGE_CHUNK - 1) / EDGE_CHUNK;
        int* myq = ctl + 8 + cls;      // per-class chunk queues
        for (;;) {
            __syncthreads();
            if (t == 0) qs = atomicAdd(myq, 1);
            __syncthreads();
            int u = qs;
            if (u >= nChunks) break;
            int base = u * EDGE_CHUNK;
            int end = min(base + EDGE_CHUNK, E);
            for (int e = base + t; e < end; e += 256) {
                int d = dstp[e];
                if (d >= lo && d < hi) {
                    int p = atomicAdd(&cnt[d], 1);
                    adj[(size_t)d * CAP + p] = src[e];
                }
            }
        }
    }
    grid_barrier(bar, 1);

    // ---- P2: gemm1  ga = dinv ⊙ (x@W1) ----
    {
        stage_W(W1, Wb, t);
        int tiles = (n + 63) / 64;
        int* myq = ctl + 16;
        int wv = t >> 6, lane = t & 63, quad = lane >> 4, m16 = lane & 15;
        for (;;) {
            __syncthreads();
            if (t == 0) qs = atomicAdd(myq, 1);
            __syncthreads();
            int u = qs;
            if (u >= tiles) break;
            int rowA = u * 64 + wv * 16 + m16;
            union { bf16x8 v; uint4 u4; } a0, a1;
            {
                float4 f0 = make_float4(0, 0, 0, 0), f1 = f0, f2 = f0, f3 = f0;
                if (rowA < n) {
                    const float* rp = &x[(size_t)rowA * 64];
                    f0 = *(const float4*)&rp[quad * 8];
                    f1 = *(const float4*)&rp[quad * 8 + 4];
                    f2 = *(const float4*)&rp[32 + quad * 8];
                    f3 = *(const float4*)&rp[32 + quad * 8 + 4];
                }
                a0.u4 = make_uint4(pack_bf16(f0.x, f0.y), pack_bf16(f0.z, f0.w),
                                   pack_bf16(f1.x, f1.y), pack_bf16(f1.z, f1.w));
                a1.u4 = make_uint4(pack_bf16(f2.x, f2.y), pack_bf16(f2.z, f2.w),
                                   pack_bf16(f3.x, f3.y), pack_bf16(f3.z, f3.w));
            }
            f32x4 acc[4];
#pragma unroll
            for (int c = 0; c < 4; c++) {
                bf16x8 b0 = *(const bf16x8*)&Wb[((size_t)(0 * 4 + c) * 64 + lane) * 8];
                bf16x8 b1 = *(const bf16x8*)&Wb[((size_t)(1 * 4 + c) * 64 + lane) * 8];
                f32x4 z = {0.f, 0.f, 0.f, 0.f};
                z = __builtin_amdgcn_mfma_f32_16x16x32_bf16(a0.v, b0, z, 0, 0, 0);
                z = __builtin_amdgcn_mfma_f32_16x16x32_bf16(a1.v, b1, z, 0, 0, 0);
                acc[c] = z;
            }
            int rowbase = u * 64 + wv * 16 + quad * 4;
            float dv[4];
#pragma unroll
            for (int r = 0; r < 4; r++) {
                int row = rowbase + r;
                dv[r] = (row < n) ? rsqrtf((float)(cnt[row] + 1)) : 0.f;
            }
#pragma unroll
            for (int c = 0; c < 4; c++) {
#pragma unroll
                for (int r = 0; r < 4; r++) {
                    int row = rowbase + r;
                    if (row < n)
                        ga[(size_t)row * 64 + c * 16 + m16] = to_bf16(acc[c][r] * dv[r]);
                }
            }
        }
    }
    grid_barrier(bar, 2);

    // ---- P3: h1 = relu(agg(ga))+x ; gb = dinv ⊙ (h1@W2) ----
    stage_W(W2, Wb, t);
    aggemm_phase(ga, cnt, adj, b1, x, h1, gb, n, ctl + 17, Wb, Afrag, dsh, &qs, t);
    grid_barrier(bar, 3);

    // ---- P4: h2 = relu(agg(gb))+h1 ; ga = dinv ⊙ (h2@W3) ----
    stage_W(W3, Wb, t);
    aggemm_phase(gb, cnt, adj, b2, h1, nullptr, ga, n, ctl + 18, Wb, Afrag, dsh, &qs, t);
    grid_barrier(bar, 4);

    // ---- P5: out = agg(ga) + b3 ----
    {
        const int lg = t & 7;
        const int c8 = lg * 8;
        const int r = t >> 3;
        const int groups = (n + 31) / 32;
        int* myq = ctl + 19;
        for (;;) {
            __syncthreads();
            if (t == 0) qs = atomicAdd(myq, 1);
            __syncthreads();
            int u = qs;
            if (u >= groups) break;
            int i = u * 32 + r;
            if (i >= n) continue;
            int deg = cnt[i];
            const int* lst = adj + (size_t)i * CAP;
            size_t rowoff = (size_t)i * 64 + c8;
            float a0 = 0.f, a1 = 0.f, a2 = 0.f, a3 = 0.f;
            float a4 = 0.f, a5 = 0.f, a6 = 0.f, a7 = 0.f;
            {   // self loop
                uint4 v = *(const uint4*)&ga[(size_t)i * 64 + c8];
                acc_bf16x2(v.x, a0, a1); acc_bf16x2(v.y, a2, a3);
                acc_bf16x2(v.z, a4, a5); acc_bf16x2(v.w, a6, a7);
            }
            gather_rows(ga, lst, deg, c8, a0, a1, a2, a3, a4, a5, a6, a7);
            float dv = rsqrtf((float)(deg + 1));
            float4 b0 = *(const float4*)&b3[c8];
            float4 b1 = *(const float4*)&b3[c8 + 4];
            float4 o0, o1;
            o0.x = dv * a0 + b0.x; o0.y = dv * a1 + b0.y;
            o0.z = dv * a2 + b0.z; o0.w = dv * a3 + b0.w;
            o1.x = dv * a4 + b1.x; o1.y = dv * a5 + b1.y;
            o1.z = dv * a6 + b1.z; o1.w = dv * a7 + b1.w;
            *(float4*)&out[rowoff] = o0;
            *(float4*)&out[rowoff + 4] = o1;
        }
    }
}

extern "C" void kernel_launch(void* const* d_in, const int* in_sizes, int n_in,
                              void* d_out, int out_size, void* d_ws, size_t ws_size,
                              hipStream_t stream) {
    const float* x  = (const float*)d_in[0];
    const int*   ei = (const int*)d_in[1];
    const float* W1 = (const float*)d_in[2];
    const float* b1 = (const float*)d_in[3];
    const float* W2 = (const float*)d_in[4];
    const float* b2 = (const float*)d_in[5];
    const float* W3 = (const float*)d_in[6];
    const float* b3 = (const float*)d_in[7];
    float* out = (float*)d_out;

    const int N = in_sizes[0] / 64;
    const int E = in_sizes[1] / 2;
    const int* src = ei;
    const int* dst = ei + E;
    const int npc = (N + 7) / 8;

    // workspace layout: [ctl 64 ints][cnt][adj][ga][gb][h1]
    char* p = (char*)d_ws;
    const int Na = ((N + 63) / 64) * 64;
    int*            ctl = (int*)p;            p += 64 * 4;
    int*            cnt = (int*)p;            p += (size_t)Na * 4;
    int*            adj = (int*)p;            p += ((size_t)N + 1) * CAP * 4;
    unsigned short* ga  = (unsigned short*)p; p += (size_t)N * 64 * 2;
    unsigned short* gb  = (unsigned short*)p; p += (size_t)N * 64 * 2;
    float*          h1  = (float*)p;          p += (size_t)N * 64 * 4;

    // zero ctl (barrier + queues) and cnt in one memset; stream-ordered
    hipMemsetAsync(ctl, 0, (64 + (size_t)Na) * 4, stream);

    gcn_mega<<<NBLK, 256, 0, stream>>>(x, src, dst, W1, b1, W2, b2, W3, b3,
                                       out, ctl, cnt, adj, ga, gb, h1,
                                       N, E, npc);
}

// Round 6
// 182.440 us; speedup vs baseline: 5.0880x; 5.0880x over previous
//
#include <hip/hip_runtime.h>
#include <hip/hip_bf16.h>

// ---------------------------------------------------------------------------
// GCN 3-layer, N=50000, E=800000, D=64, fp32 in/out.
// R19: revert R18 mega-kernel (928us: spin-barrier atomic herd serialized
// queue draws; counters showed VALUBusy 2.75%, 280 GB/s effective). Back to
// R15 multi-dispatch (182us) + three fixes informed by the mega counters
// (pipeline traffic FETCH 148MB / WRITE 79MB, writes ~31MB over budget):
//  (a) gather row-load DOUBLE-BUFFER: consume w_k then immediately reissue
//      it with batch b+1's row (indices prefetched 2 batches ahead) — ~8
//      loads in flight through the acc chain, no extra register set.
//  (b) h1 stored bf16 (saves 12.8MB r+w; residual rounding ~+0.005 absmax,
//      threshold 0.035, measured 0.0078 — safe).
//  (c) g_out via LDS-transpose (reuse Afrag/Wb, no LDS growth): each wave
//      stores full 128B lines instead of 32B fragments (write-allocate cut).
// R15: index prefetch, stage_W after Phase A, dinv via LDS. R14: 32
// nodes/block, launch_bounds(256,4). R13: agg+gemm fusion through LDS.
// R8/R12 gather floor form, XCD-partitioned fill (R3/R4), bf16 table (R6),
// MFMA 16x16x32 gemm (R8).
// ---------------------------------------------------------------------------

#define CAP 64
#define EDGE_CHUNK 1024

typedef __attribute__((ext_vector_type(8))) short bf16x8;
typedef __attribute__((ext_vector_type(4))) float f32x4;

// --- pack two fp32 -> bf16x2 (RNE) ----------------------------------------
__device__ inline unsigned pack_bf16(float a, float b) {
    union { float f; unsigned i; } ua, ub;
    ua.f = a; ub.f = b;
    unsigned x = (ua.i + 0x7fffu + ((ua.i >> 16) & 1u)) >> 16;
    unsigned y = (ub.i + 0x7fffu + ((ub.i >> 16) & 1u)) >> 16;
    return x | (y << 16);
}
__device__ inline unsigned short to_bf16(float a) {
    union { float f; unsigned i; } u; u.f = a;
    return (unsigned short)((u.i + 0x7fffu + ((u.i >> 16) & 1u)) >> 16);
}
// --- accumulate bf16x2 (packed uint) into two floats ----------------------
__device__ inline void acc_bf16x2(unsigned u, float& a, float& b) {
    union { unsigned i; float f; } lo, hi;
    lo.i = u << 16;
    hi.i = u & 0xffff0000u;
    a += lo.f; b += hi.f;
}

// --- 8-lane/node uint4 row gather, double-buffered (R19) ------------------
// Indices prefetched 2 batches ahead; each row register is reissued with the
// next batch's row immediately after its accumulation, keeping ~8 row loads
// in flight across the acc chain. Accumulation order identical to R15.
__device__ inline void gather_rows(const unsigned short* __restrict__ g,
                                   const int* __restrict__ lst, int deg, int c8,
                                   float& a0, float& a1, float& a2, float& a3,
                                   float& a4, float& a5, float& a6, float& a7) {
    int nfull = deg >> 3;              // full 8-batches
    int4 ja, jb, na, nb;
    uint4 w0, w1, w2, w3, w4, w5, w6, w7;
    if (nfull > 0) {
        ja = *(const int4*)&lst[0]; jb = *(const int4*)&lst[4];
        w0 = *(const uint4*)&g[(size_t)ja.x * 64 + c8];
        w1 = *(const uint4*)&g[(size_t)ja.y * 64 + c8];
        w2 = *(const uint4*)&g[(size_t)ja.z * 64 + c8];
        w3 = *(const uint4*)&g[(size_t)ja.w * 64 + c8];
        w4 = *(const uint4*)&g[(size_t)jb.x * 64 + c8];
        w5 = *(const uint4*)&g[(size_t)jb.y * 64 + c8];
        w6 = *(const uint4*)&g[(size_t)jb.z * 64 + c8];
        w7 = *(const uint4*)&g[(size_t)jb.w * 64 + c8];
        if (nfull > 1) { na = *(const int4*)&lst[8]; nb = *(const int4*)&lst[12]; }
    }
    for (int b = 0; b < nfull; b++) {
        bool has1 = (b + 1 < nfull);
        bool has2 = (b + 2 < nfull);
        int4 ta, tb;
        if (has2) {
            ta = *(const int4*)&lst[(b + 2) * 8];
            tb = *(const int4*)&lst[(b + 2) * 8 + 4];
        }
        acc_bf16x2(w0.x, a0, a1); acc_bf16x2(w0.y, a2, a3);
        acc_bf16x2(w0.z, a4, a5); acc_bf16x2(w0.w, a6, a7);
        if (has1) w0 = *(const uint4*)&g[(size_t)na.x * 64 + c8];
        acc_bf16x2(w1.x, a0, a1); acc_bf16x2(w1.y, a2, a3);
        acc_bf16x2(w1.z, a4, a5); acc_bf16x2(w1.w, a6, a7);
        if (has1) w1 = *(const uint4*)&g[(size_t)na.y * 64 + c8];
        acc_bf16x2(w2.x, a0, a1); acc_bf16x2(w2.y, a2, a3);
        acc_bf16x2(w2.z, a4, a5); acc_bf16x2(w2.w, a6, a7);
        if (has1) w2 = *(const uint4*)&g[(size_t)na.z * 64 + c8];
        acc_bf16x2(w3.x, a0, a1); acc_bf16x2(w3.y, a2, a3);
        acc_bf16x2(w3.z, a4, a5); acc_bf16x2(w3.w, a6, a7);
        if (has1) w3 = *(const uint4*)&g[(size_t)na.w * 64 + c8];
        acc_bf16x2(w4.x, a0, a1); acc_bf16x2(w4.y, a2, a3);
        acc_bf16x2(w4.z, a4, a5); acc_bf16x2(w4.w, a6, a7);
        if (has1) w4 = *(const uint4*)&g[(size_t)nb.x * 64 + c8];
        acc_bf16x2(w5.x, a0, a1); acc_bf16x2(w5.y, a2, a3);
        acc_bf16x2(w5.z, a4, a5); acc_bf16x2(w5.w, a6, a7);
        if (has1) w5 = *(const uint4*)&g[(size_t)nb.y * 64 + c8];
        acc_bf16x2(w6.x, a0, a1); acc_bf16x2(w6.y, a2, a3);
        acc_bf16x2(w6.z, a4, a5); acc_bf16x2(w6.w, a6, a7);
        if (has1) w6 = *(const uint4*)&g[(size_t)nb.z * 64 + c8];
        acc_bf16x2(w7.x, a0, a1); acc_bf16x2(w7.y, a2, a3);
        acc_bf16x2(w7.z, a4, a5); acc_bf16x2(w7.w, a6, a7);
        if (has1) w7 = *(const uint4*)&g[(size_t)nb.w * 64 + c8];
        if (has2) { na = ta; nb = tb; }
    }
    int k = nfull * 8;
    if (k + 4 <= deg) {
        int4 j4 = *(const int4*)&lst[k];
        uint4 t0 = *(const uint4*)&g[(size_t)j4.x * 64 + c8];
        uint4 t1 = *(const uint4*)&g[(size_t)j4.y * 64 + c8];
        uint4 t2 = *(const uint4*)&g[(size_t)j4.z * 64 + c8];
        uint4 t3 = *(const uint4*)&g[(size_t)j4.w * 64 + c8];
        acc_bf16x2(t0.x, a0, a1); acc_bf16x2(t0.y, a2, a3);
        acc_bf16x2(t0.z, a4, a5); acc_bf16x2(t0.w, a6, a7);
        acc_bf16x2(t1.x, a0, a1); acc_bf16x2(t1.y, a2, a3);
        acc_bf16x2(t1.z, a4, a5); acc_bf16x2(t1.w, a6, a7);
        acc_bf16x2(t2.x, a0, a1); acc_bf16x2(t2.y, a2, a3);
        acc_bf16x2(t2.z, a4, a5); acc_bf16x2(t2.w, a6, a7);
        acc_bf16x2(t3.x, a0, a1); acc_bf16x2(t3.y, a2, a3);
        acc_bf16x2(t3.z, a4, a5); acc_bf16x2(t3.w, a6, a7);
        k += 4;
    }
    for (; k < deg; k++) {
        uint4 v = *(const uint4*)&g[(size_t)lst[k] * 64 + c8];
        acc_bf16x2(v.x, a0, a1); acc_bf16x2(v.y, a2, a3);
        acc_bf16x2(v.z, a4, a5); acc_bf16x2(v.w, a6, a7);
    }
}

// --- fused count+place: slot = atomicAdd(cnt), XCD-partitioned by dst -----
__global__ void fill_kernel(const int* __restrict__ src, const int* __restrict__ dst,
                            int* __restrict__ cnt, int* __restrict__ adj,
                            int E, int npc) {
    int cls = blockIdx.x & 7;          // -> XCD (round-robin heuristic)
    int base = (blockIdx.x >> 3) * EDGE_CHUNK;
    int end = min(base + EDGE_CHUNK, E);
    int lo = cls * npc, hi = lo + npc;
    for (int e = base + threadIdx.x; e < end; e += blockDim.x) {
        int d = dst[e];
        if (d >= lo && d < hi) {
            int p = atomicAdd(&cnt[d], 1);
            adj[(size_t)d * CAP + p] = src[e];
        }
    }
}

// --- stage W (fp32 64x64) into B-fragment order (bf16) in LDS -------------
__device__ inline void stage_W(const float* __restrict__ W, unsigned short* Wb, int t) {
#pragma unroll
    for (int e0 = 0; e0 < 2; e0++) {
        int e = t + e0 * 256;          // frag index 0..511
        int sc = e >> 6;               // s*4 + c
        int l  = e & 63;               // target lane
        int s = sc >> 2, c = sc & 3;
        int nn = c * 16 + (l & 15);
        int kb = s * 32 + (l >> 4) * 8;
        const float* wp = &W[(size_t)kb * 64 + nn];
        unsigned q0 = pack_bf16(wp[0 * 64], wp[1 * 64]);
        unsigned q1 = pack_bf16(wp[2 * 64], wp[3 * 64]);
        unsigned q2 = pack_bf16(wp[4 * 64], wp[5 * 64]);
        unsigned q3 = pack_bf16(wp[6 * 64], wp[7 * 64]);
        *(uint4*)&Wb[e * 8] = make_uint4(q0, q1, q2, q3);
    }
}

// --- g(bf16) = dinv ⊙ (in @ W) via MFMA; 64 rows/block (layer 1 only) -----
// R19: output staged through Wb-as-Ofrag (free after MFMA) for coalesced
// 16B/lane stores.
__global__ __launch_bounds__(256, 4) void gemm_kernel(const float* __restrict__ in,
                                                      const float* __restrict__ W,
                                                      const int* __restrict__ cnt,
                                                      unsigned short* __restrict__ g, int n) {
    __shared__ unsigned short Wb[512 * 8];     // B-frags, then out-tile alias
    int t = threadIdx.x;
    stage_W(W, Wb, t);

    int wv = t >> 6;
    int lane = t & 63;
    int quad = lane >> 4;
    int m16 = lane & 15;

    int rowA = blockIdx.x * 64 + wv * 16 + m16;
    union { bf16x8 v; uint4 u; } a0, a1;
    {
        float4 f0 = make_float4(0, 0, 0, 0), f1 = f0, f2 = f0, f3 = f0;
        if (rowA < n) {
            const float* rp = &in[(size_t)rowA * 64];
            f0 = *(const float4*)&rp[quad * 8];
            f1 = *(const float4*)&rp[quad * 8 + 4];
            f2 = *(const float4*)&rp[32 + quad * 8];
            f3 = *(const float4*)&rp[32 + quad * 8 + 4];
        }
        a0.u = make_uint4(pack_bf16(f0.x, f0.y), pack_bf16(f0.z, f0.w),
                          pack_bf16(f1.x, f1.y), pack_bf16(f1.z, f1.w));
        a1.u = make_uint4(pack_bf16(f2.x, f2.y), pack_bf16(f2.z, f2.w),
                          pack_bf16(f3.x, f3.y), pack_bf16(f3.z, f3.w));
    }
    __syncthreads();

    f32x4 acc[4];
#pragma unroll
    for (int c = 0; c < 4; c++) {
        bf16x8 b0 = *(const bf16x8*)&Wb[((size_t)(0 * 4 + c) * 64 + lane) * 8];
        bf16x8 b1 = *(const bf16x8*)&Wb[((size_t)(1 * 4 + c) * 64 + lane) * 8];
        f32x4 z = {0.f, 0.f, 0.f, 0.f};
        z = __builtin_amdgcn_mfma_f32_16x16x32_bf16(a0.v, b0, z, 0, 0, 0);
        z = __builtin_amdgcn_mfma_f32_16x16x32_bf16(a1.v, b1, z, 0, 0, 0);
        acc[c] = z;
    }

    int lrow = wv * 16 + quad * 4;            // local row base 0..63
    float dv[4];
#pragma unroll
    for (int r = 0; r < 4; r++) {
        int row = blockIdx.x * 64 + lrow + r;
        dv[r] = (row < n) ? rsqrtf((float)(cnt[row] + 1)) : 0.f;
    }
    __syncthreads();                          // Wb B-frag reads all done
    unsigned short* Ofrag = Wb;               // 64x64 ushort = 8KB alias
#pragma unroll
    for (int c = 0; c < 4; c++) {
#pragma unroll
        for (int r = 0; r < 4; r++)
            Ofrag[(size_t)(lrow + r) * 64 + c * 16 + m16] = to_bf16(acc[c][r] * dv[r]);
    }
    __syncthreads();
#pragma unroll
    for (int it = 0; it < 2; it++) {
        int unit = t + it * 256;              // 512 units: 64 rows x 8 chunks
        int row = unit >> 3, chv = unit & 7;
        int grow = blockIdx.x * 64 + row;
        if (grow < n)
            *(uint4*)&g[(size_t)grow * 64 + chv * 8] =
                *(const uint4*)&Ofrag[(size_t)row * 64 + chv * 8];
    }
}

// --- fused agg(l) + gemm(l+1); 32 nodes/block (R14/R15/R19) ---------------
// Phase A: dbuf uint4 gather (8 lanes/node); h = relu(dinv*sum+bias)+res;
// h written bf16 (WRITE_H); deposit h into A-frag LDS + dinv into LDS.
// Phase B: MFMA, then out-tile staged back into Afrag for coalesced stores.
template <int WRITE_H, int RES_BF16>
__global__ __launch_bounds__(256, 4) void aggemm_kernel(
        const unsigned short* __restrict__ g_in,
        const int* __restrict__ cnt,
        const int* __restrict__ adj,
        const float* __restrict__ bias,
        const void* __restrict__ res_p,
        const float* __restrict__ W,
        unsigned short* __restrict__ h_out,   // bf16 h (if WRITE_H)
        unsigned short* __restrict__ g_out,
        int n) {
    __shared__ unsigned short Wb[512 * 8];     // 8 KB B-frags
    __shared__ unsigned short Afrag[2048];     // 4 KB A-frags, then out-tile
    __shared__ float dsh[32];                  // per-node dinv for Phase B
    int t = threadIdx.x;

    // ---- Phase A: aggregate 32 nodes, 8 lanes/node, uint4 ----
    int r  = t >> 3;                   // node-in-block 0..31
    int lg = t & 7;
    const int c8 = lg * 8;
    int i = blockIdx.x * 32 + r;
    float v0 = 0.f, v1 = 0.f, v2 = 0.f, v3 = 0.f;
    float v4 = 0.f, v5 = 0.f, v6 = 0.f, v7 = 0.f;
    float dvv = 0.f;
    if (i < n) {
        int deg = cnt[i];
        const int* lst = adj + (size_t)i * CAP;
        float r0 = 0.f, r1 = 0.f, r2 = 0.f, r3 = 0.f;
        float r4 = 0.f, r5 = 0.f, r6 = 0.f, r7 = 0.f;
        if (RES_BF16) {                // hoisted residual load (bf16 h1)
            const unsigned short* rp = (const unsigned short*)res_p;
            uint4 rv = *(const uint4*)&rp[(size_t)i * 64 + c8];
            acc_bf16x2(rv.x, r0, r1); acc_bf16x2(rv.y, r2, r3);
            acc_bf16x2(rv.z, r4, r5); acc_bf16x2(rv.w, r6, r7);
        } else {                       // fp32 residual (x)
            const float* rp = (const float*)res_p;
            float4 q0 = *(const float4*)&rp[(size_t)i * 64 + c8];
            float4 q1 = *(const float4*)&rp[(size_t)i * 64 + c8 + 4];
            r0 = q0.x; r1 = q0.y; r2 = q0.z; r3 = q0.w;
            r4 = q1.x; r5 = q1.y; r6 = q1.z; r7 = q1.w;
        }
        float a0 = 0.f, a1 = 0.f, a2 = 0.f, a3 = 0.f;
        float a4 = 0.f, a5 = 0.f, a6 = 0.f, a7 = 0.f;
        {   // self loop
            uint4 v = *(const uint4*)&g_in[(size_t)i * 64 + c8];
            acc_bf16x2(v.x, a0, a1); acc_bf16x2(v.y, a2, a3);
            acc_bf16x2(v.z, a4, a5); acc_bf16x2(v.w, a6, a7);
        }
        gather_rows(g_in, lst, deg, c8, a0, a1, a2, a3, a4, a5, a6, a7);
        dvv = rsqrtf((float)(deg + 1));
        float4 b0 = *(const float4*)&bias[c8];
        float4 b1 = *(const float4*)&bias[c8 + 4];
        v0 = fmaxf(dvv * a0 + b0.x, 0.f) + r0;
        v1 = fmaxf(dvv * a1 + b0.y, 0.f) + r1;
        v2 = fmaxf(dvv * a2 + b0.z, 0.f) + r2;
        v3 = fmaxf(dvv * a3 + b0.w, 0.f) + r3;
        v4 = fmaxf(dvv * a4 + b1.x, 0.f) + r4;
        v5 = fmaxf(dvv * a5 + b1.y, 0.f) + r5;
        v6 = fmaxf(dvv * a6 + b1.z, 0.f) + r6;
        v7 = fmaxf(dvv * a7 + b1.w, 0.f) + r7;
    }
    // pack h row chunk once: reused for h_out write and A-frag deposit
    uint4 pk;
    pk.x = pack_bf16(v0, v1);
    pk.y = pack_bf16(v2, v3);
    pk.z = pack_bf16(v4, v5);
    pk.w = pack_bf16(v6, v7);
    if (WRITE_H && i < n)
        *(uint4*)&h_out[(size_t)i * 64 + c8] = pk;
    // stage W after the gather (R15): latency hides under other waves' A.
    stage_W(W, Wb, t);
    {
        int sA = r >> 4, mA = r & 15;
        *(uint4*)&Afrag[((size_t)(sA * 8 + lg) * 16 + mA) * 8] = pk;
        if (lg == 0) dsh[r] = dvv;
    }
    __syncthreads();

    // ---- Phase B: MFMA gemm on the 32-row tile ----
    int wv = t >> 6;
    int lane = t & 63;
    int quad = lane >> 4;
    int m16 = lane & 15;
    int sB = wv & 1;                   // row sub-tile 0..1
    int ch = wv >> 1;                  // col half 0..1
    bf16x8 af0 = *(const bf16x8*)&Afrag[((size_t)(sB * 8 + quad) * 16 + m16) * 8];
    bf16x8 af1 = *(const bf16x8*)&Afrag[((size_t)(sB * 8 + 4 + quad) * 16 + m16) * 8];
    int lrow = sB * 16 + quad * 4;     // local row 0..31
    float dv2[4];
#pragma unroll
    for (int rr = 0; rr < 4; rr++)
        dv2[rr] = dsh[lrow + rr];
    __syncthreads();                   // all A-frag reads done before overwrite
    f32x4 acc[2];
#pragma unroll
    for (int c2 = 0; c2 < 2; c2++) {
        int c = ch * 2 + c2;
        bf16x8 b0 = *(const bf16x8*)&Wb[((size_t)(0 * 4 + c) * 64 + lane) * 8];
        bf16x8 b1 = *(const bf16x8*)&Wb[((size_t)(1 * 4 + c) * 64 + lane) * 8];
        f32x4 z = {0.f, 0.f, 0.f, 0.f};
        z = __builtin_amdgcn_mfma_f32_16x16x32_bf16(af0, b0, z, 0, 0, 0);
        z = __builtin_amdgcn_mfma_f32_16x16x32_bf16(af1, b1, z, 0, 0, 0);
        acc[c2] = z;
    }
    // stage out-tile into Afrag [32][64] for coalesced stores
#pragma unroll
    for (int c2 = 0; c2 < 2; c2++) {
        int c = ch * 2 + c2;
#pragma unroll
        for (int rr = 0; rr < 4; rr++)
            Afrag[(size_t)(lrow + rr) * 64 + c * 16 + m16] = to_bf16(acc[c2][rr] * dv2[rr]);
    }
    __syncthreads();
    {
        int orow = blockIdx.x * 32 + r;
        if (orow < n)
            *(uint4*)&g_out[(size_t)orow * 64 + c8] =
                *(const uint4*)&Afrag[(size_t)r * 64 + c8];
    }
}

// --- final aggregation: 8 lanes/node uint4, dbuf gather -------------------
__global__ __launch_bounds__(256, 4) void agg_kernel(const unsigned short* __restrict__ g,
                                                     const int* __restrict__ cnt,
                                                     const int* __restrict__ adj,
                                                     const float* __restrict__ bias,
                                                     float* __restrict__ out, int n) {
    int t = threadIdx.x;
    int lg = t & 7;
    int i = blockIdx.x * 32 + (t >> 3);
    if (i >= n) return;
    int deg = cnt[i];
    const int* lst = adj + (size_t)i * CAP;
    const int c8 = lg * 8;
    size_t rowoff = (size_t)i * 64 + c8;
    float a0 = 0.f, a1 = 0.f, a2 = 0.f, a3 = 0.f;
    float a4 = 0.f, a5 = 0.f, a6 = 0.f, a7 = 0.f;
    {   // self loop
        uint4 v = *(const uint4*)&g[(size_t)i * 64 + c8];
        acc_bf16x2(v.x, a0, a1); acc_bf16x2(v.y, a2, a3);
        acc_bf16x2(v.z, a4, a5); acc_bf16x2(v.w, a6, a7);
    }
    gather_rows(g, lst, deg, c8, a0, a1, a2, a3, a4, a5, a6, a7);
    float dv = rsqrtf((float)(deg + 1));
    float4 b0 = *(const float4*)&bias[c8];
    float4 b1 = *(const float4*)&bias[c8 + 4];
    float4 o0, o1;
    o0.x = dv * a0 + b0.x; o0.y = dv * a1 + b0.y;
    o0.z = dv * a2 + b0.z; o0.w = dv * a3 + b0.w;
    o1.x = dv * a4 + b1.x; o1.y = dv * a5 + b1.y;
    o1.z = dv * a6 + b1.z; o1.w = dv * a7 + b1.w;
    *(float4*)&out[rowoff] = o0;
    *(float4*)&out[rowoff + 4] = o1;
}

extern "C" void kernel_launch(void* const* d_in, const int* in_sizes, int n_in,
                              void* d_out, int out_size, void* d_ws, size_t ws_size,
                              hipStream_t stream) {
    const float* x  = (const float*)d_in[0];
    const int*   ei = (const int*)d_in[1];
    const float* W1 = (const float*)d_in[2];
    const float* b1 = (const float*)d_in[3];
    const float* W2 = (const float*)d_in[4];
    const float* b2 = (const float*)d_in[5];
    const float* W3 = (const float*)d_in[6];
    const float* b3 = (const float*)d_in[7];
    float* out = (float*)d_out;

    const int N = in_sizes[0] / 64;
    const int E = in_sizes[1] / 2;
    const int* src = ei;
    const int* dst = ei + E;
    const int npc = (N + 7) / 8;
    const int nEdgeChunks = (E + EDGE_CHUNK - 1) / EDGE_CHUNK;

    // workspace layout
    char* p = (char*)d_ws;
    const int Na = ((N + 63) / 64) * 64;
    int*            cnt = (int*)p;            p += (size_t)Na * 4;
    int*            adj = (int*)p;            p += ((size_t)N + 1) * CAP * 4;
    unsigned short* ga  = (unsigned short*)p; p += (size_t)N * 64 * 2;
    unsigned short* gb  = (unsigned short*)p; p += (size_t)N * 64 * 2;
    unsigned short* h1  = (unsigned short*)p; p += (size_t)N * 64 * 2;   // bf16

    const int tileBlocks = (N + 63) / 64;   // gemm (64-row MFMA tiles)
    const int halfBlocks = (N + 31) / 32;   // aggemm + final agg (32 nodes)

    // --- bucket adjacency build (ws re-poisoned every call) ---
    hipMemsetAsync(cnt, 0, (size_t)N * 4, stream);
    fill_kernel<<<nEdgeChunks * 8, 256, 0, stream>>>(src, dst, cnt, adj, E, npc);

    // --- layer 1 gemm: ga = dinv ⊙ (x@W1) ---
    gemm_kernel<<<tileBlocks, 256, 0, stream>>>(x, W1, cnt, ga, N);
    // --- fused: h1 = relu(agg(ga))+x (bf16) ; gb = dinv ⊙ (h1@W2) ---
    aggemm_kernel<1, 0><<<halfBlocks, 256, 0, stream>>>(ga, cnt, adj, b1, (const void*)x,
                                                        W2, h1, gb, N);
    // --- fused: h2 = relu(agg(gb))+h1 ; ga = dinv ⊙ (h2@W3) ---
    aggemm_kernel<0, 1><<<halfBlocks, 256, 0, stream>>>(gb, cnt, adj, b2, (const void*)h1,
                                                        W3, nullptr, ga, N);
    // --- final: out = agg(ga) + b3 ---
    agg_kernel<<<halfBlocks, 256, 0, stream>>>(ga, cnt, adj, b3, out, N);
}